// Round 2
// baseline (109.704 us; speedup 1.0000x reference)
//
#include <hip/hip_runtime.h>
#include <stdint.h>

#define NB 4
#define SS 192
#define NI 256

typedef __attribute__((ext_vector_type(8))) short bf16x8;
typedef __attribute__((ext_vector_type(4))) float f32x4;

__device__ __forceinline__ uint16_t f2bf(float f) {
  union { float f; uint32_t u; } v; v.f = f;
  return (uint16_t)((v.u + 0x7FFFu + ((v.u >> 16) & 1u)) >> 16);
}

// multiply two packed bf16 pairs (in a u32), result packed bf16 pair
__device__ __forceinline__ uint32_t bfmul2(uint32_t x, uint32_t y) {
  union { float f; uint32_t u; } xa, xb, ya, yb, r0, r1;
  xa.u = x << 16;        ya.u = y << 16;
  xb.u = x & 0xFFFF0000u; yb.u = y & 0xFFFF0000u;
  r0.f = xa.f * ya.f;
  r1.f = xb.f * yb.f;
  uint32_t lo = (r0.u + 0x7FFFu + ((r0.u >> 16) & 1u)) >> 16;
  uint32_t hi = (r1.u + 0x7FFFu + ((r1.u >> 16) & 1u)) >> 16;
  return lo | (hi << 16);
}

// ---------------- K1: reduce W_tri over (j,k) -> partial sums ----------------
// 1024 blocks, each sums 16384 contiguous floats (4 blocks per i-row).
__global__ void k_wtri_partial(const float* __restrict__ W, float* __restrict__ partial) {
  const int bi = blockIdx.x, tid = threadIdx.x;
  const float4* p = (const float4*)(W + (size_t)bi * 16384);
  float s = 0.f;
  #pragma unroll
  for (int it = 0; it < 16; ++it) {
    float4 v = p[it * 256 + tid];
    s += v.x + v.y + v.z + v.w;
  }
  for (int off = 32; off > 0; off >>= 1) s += __shfl_down(s, off, 64);
  __shared__ float red[4];
  if ((tid & 63) == 0) red[tid >> 6] = s;
  __syncthreads();
  if (tid == 0) partial[bi] = red[0] + red[1] + red[2] + red[3];
}

// ---------------- K2: projections hU = h_head*U, hV = h_head*V, dZ = h_dep*Z ----------------
// grid (96, 3), 256 threads. Block handles 8 rows x 256 cols for one matrix.
__global__ void k_proj(const float* __restrict__ h_head, const float* __restrict__ h_dep,
                       const float* __restrict__ U, const float* __restrict__ V, const float* __restrict__ Z,
                       float* __restrict__ hU, float* __restrict__ hV, float* __restrict__ dZ) {
  const int which = blockIdx.y;
  const int r0 = blockIdx.x * 8;
  const int tid = threadIdx.x;
  const float* A = (which == 2) ? h_dep : h_head;
  const float* M = (which == 0) ? U : (which == 1) ? V : Z;
  float* out = (which == 0) ? hU : (which == 1) ? hV : dZ;
  __shared__ float ah[8][NI];
  #pragma unroll
  for (int r = 0; r < 8; ++r) ah[r][tid] = A[(r0 + r) * NI + tid];
  __syncthreads();
  float acc[8] = {};
  for (int i = 0; i < NI; ++i) {
    float m = M[i * NI + tid];
    #pragma unroll
    for (int r = 0; r < 8; ++r) acc[r] += ah[r][i] * m;
  }
  #pragma unroll
  for (int r = 0; r < 8; ++r) out[(r0 + r) * NI + tid] = acc[r];
}

// ---------------- K2b: finish w_red + bf16 conversions (HW = h_head*w_red, HD, HS) ----------------
__global__ void k_tobf16(const float* __restrict__ h_head, const float* __restrict__ h_dep,
                         const float* __restrict__ h_sib, const float* __restrict__ partial,
                         uint16_t* __restrict__ HW, uint16_t* __restrict__ HD, uint16_t* __restrict__ HS) {
  const int g = blockIdx.x * 256 + threadIdx.x;
  const int i = threadIdx.x;            // i == threadIdx.x since NI==256
  const float w = partial[4 * i] + partial[4 * i + 1] + partial[4 * i + 2] + partial[4 * i + 3];
  HW[g] = f2bf(h_head[g] * w);
  HD[g] = f2bf(h_dep[g]);
  HS[g] = f2bf(h_sib[g]);
}

// ---------------- K3: biaffine score matrices ----------------
// grid (24, 4, 3): (x-tile of 8, b, which). 192 threads = y index.
__global__ void k_scores(const float* __restrict__ hU, const float* __restrict__ hV, const float* __restrict__ dZ,
                         const float* __restrict__ h_dep, const float* __restrict__ h_sib,
                         float* __restrict__ s_hd, float* __restrict__ s_hs, float* __restrict__ s_ds) {
  const int which = blockIdx.z, b = blockIdx.y, x0 = blockIdx.x * 8;
  const int tid = threadIdx.x; // 0..191
  const float* A = (which == 0) ? hU : (which == 1) ? hV : dZ;
  const float* B = (which == 0) ? h_dep : h_sib;
  float* out = (which == 0) ? s_hd : (which == 1) ? s_hs : s_ds;
  __shared__ float ar[8][NI];
  for (int idx = tid; idx < 8 * NI; idx += 192)
    ar[idx >> 8][idx & 255] = A[(b * SS + x0 + (idx >> 8)) * NI + (idx & 255)];
  __syncthreads();
  const float4* bp = (const float4*)(B + (b * SS + tid) * NI);
  float acc[8] = {};
  for (int c = 0; c < NI / 4; ++c) {
    float4 bv = bp[c];
    #pragma unroll
    for (int r = 0; r < 8; ++r) {
      float4 av = ((const float4*)ar[r])[c];
      acc[r] += av.x * bv.x + av.y * bv.y + av.z * bv.z + av.w * bv.w;
    }
  }
  #pragma unroll
  for (int r = 0; r < 8; ++r) out[(b * SS + x0 + r) * SS + tid] = acc[r];
}

// ---------------- K4: main GEMM with h-axis reuse ----------------
// out[b,h,d,s] = sum_i (HD[bd,i]*HS[bs,i]) * HW[bh,i]  + epilogue adds.
// grid (192, 3, 4) = (d, s-tile, b). 256 threads = 4 waves, each M=64 x N=48.
__global__ __launch_bounds__(256, 2) void k_big(
    const uint16_t* __restrict__ HW, const uint16_t* __restrict__ HD, const uint16_t* __restrict__ HS,
    const float* __restrict__ s_hd, const float* __restrict__ s_hs, const float* __restrict__ s_ds,
    const float* __restrict__ bias, float* __restrict__ out) {
  __shared__ __align__(16) unsigned char lds[32768];  // A-tile [64][256] bf16, swizzled
  const int d = blockIdx.x, s0 = blockIdx.y * 64, b = blockIdx.z;
  const int tid = threadIdx.x;

  // ---- stage A[r][k] = HD[b,d,k] * HS[b,s0+r,k] in bf16, XOR-swizzled ----
  const int col8 = tid & 31;   // 16B chunk index within a 512B row
  const uint4 hd4 = *(const uint4*)(HD + (b * SS + d) * NI + col8 * 8);
  #pragma unroll
  for (int it = 0; it < 8; ++it) {
    const int row = it * 8 + (tid >> 5);
    const uint4 hs4 = *(const uint4*)(HS + (b * SS + s0 + row) * NI + col8 * 8);
    uint4 a4;
    a4.x = bfmul2(hs4.x, hd4.x);
    a4.y = bfmul2(hs4.y, hd4.y);
    a4.z = bfmul2(hs4.z, hd4.z);
    a4.w = bfmul2(hs4.w, hd4.w);
    const int swz = ((row << 9) | (col8 << 4)) ^ ((row & 7) << 4);
    *(uint4*)(lds + swz) = a4;
  }
  __syncthreads();

  // ---- MFMA: M=64 (s), N=48 (h) per wave, K=256 in 8 steps ----
  const int lane = tid & 63, w = tid >> 6;
  const int n0 = w * 48;               // h base for this wave
  const int fr = lane & 15;
  const int lg = lane >> 4;
  const int kb = lg * 8;
  const uint16_t* hwb = HW + (b * SS) * NI;
  f32x4 acc[4][3] = {};
  #pragma unroll
  for (int ks = 0; ks < 8; ++ks) {
    const int k = ks * 32 + kb;
    const int k2 = k * 2;
    bf16x8 a[4], bb[3];
    #pragma unroll
    for (int mt = 0; mt < 4; ++mt) {
      const int r = mt * 16 + fr;
      const int off = ((r << 9) + k2) ^ ((r & 7) << 4);
      a[mt] = *reinterpret_cast<const bf16x8*>(lds + off);
    }
    #pragma unroll
    for (int nt = 0; nt < 3; ++nt) {
      const int h = n0 + nt * 16 + fr;
      bb[nt] = *reinterpret_cast<const bf16x8*>(hwb + h * NI + k);
    }
    #pragma unroll
    for (int mt = 0; mt < 4; ++mt)
      #pragma unroll
      for (int nt = 0; nt < 3; ++nt)
        acc[mt][nt] = __builtin_amdgcn_mfma_f32_16x16x32_bf16(a[mt], bb[nt], acc[mt][nt], 0, 0, 0);
  }

  // ---- epilogue: + s_hd[b,h,d] + s_hs[b,h,s] + s_ds[b,d,s] + bias ----
  const float bias0 = bias[0];
  float c0[3];
  #pragma unroll
  for (int nt = 0; nt < 3; ++nt) {
    const int h = n0 + nt * 16 + fr;
    c0[nt] = s_hd[(b * SS + h) * SS + d] + bias0;
  }
  #pragma unroll
  for (int mt = 0; mt < 4; ++mt) {
    const int s = s0 + mt * 16 + lg * 4;
    const float4 ds4 = *(const float4*)(s_ds + (b * SS + d) * SS + s);
    #pragma unroll
    for (int nt = 0; nt < 3; ++nt) {
      const int h = n0 + nt * 16 + fr;
      const int bh = b * SS + h;
      const float4 hs4 = *(const float4*)(s_hs + bh * SS + s);
      float4 v;
      v.x = acc[mt][nt][0] + c0[nt] + hs4.x + ds4.x;
      v.y = acc[mt][nt][1] + c0[nt] + hs4.y + ds4.y;
      v.z = acc[mt][nt][2] + c0[nt] + hs4.z + ds4.z;
      v.w = acc[mt][nt][3] + c0[nt] + hs4.w + ds4.w;
      *(float4*)(out + ((size_t)bh * SS + d) * SS + s) = v;
    }
  }
}

extern "C" void kernel_launch(void* const* d_in, const int* in_sizes, int n_in,
                              void* d_out, int out_size, void* d_ws, size_t ws_size,
                              hipStream_t stream) {
  const float* h_head = (const float*)d_in[0];
  const float* h_dep  = (const float*)d_in[1];
  const float* h_sib  = (const float*)d_in[2];
  const float* W_tri  = (const float*)d_in[3];
  const float* U_hd   = (const float*)d_in[4];
  const float* V_hs   = (const float*)d_in[5];
  const float* Z_ds   = (const float*)d_in[6];
  const float* bias   = (const float*)d_in[7];
  float* out = (float*)d_out;

  // workspace carve-up (~5.1 MB total)
  float* partial = (float*)d_ws;              // 1024
  float* hU      = partial + 1024;            // 768*256
  float* hV      = hU + 768 * NI;
  float* dZ      = hV + 768 * NI;
  float* s_hd    = dZ + 768 * NI;             // 4*192*192
  float* s_hs    = s_hd + NB * SS * SS;
  float* s_ds    = s_hs + NB * SS * SS;
  uint16_t* HW   = (uint16_t*)(s_ds + NB * SS * SS);  // 768*256 bf16
  uint16_t* HD   = HW + 768 * NI;
  uint16_t* HS   = HD + 768 * NI;

  k_wtri_partial<<<1024, 256, 0, stream>>>(W_tri, partial);
  k_proj<<<dim3(96, 3), 256, 0, stream>>>(h_head, h_dep, U_hd, V_hs, Z_ds, hU, hV, dZ);
  k_tobf16<<<768, 256, 0, stream>>>(h_head, h_dep, h_sib, partial, HW, HD, HS);
  k_scores<<<dim3(24, 4, 3), 192, 0, stream>>>(hU, hV, dZ, h_dep, h_sib, s_hd, s_hs, s_ds);
  k_big<<<dim3(SS, 3, NB), 256, 0, stream>>>(HW, HD, HS, s_hd, s_hs, s_ds, bias, out);
}